// Round 26
// baseline (119.060 us; speedup 1.0000x reference)
//
#include <hip/hip_runtime.h>
#include <stdint.h>
#include <stddef.h>

#define T_ 2048
#define D_ 1024
#define H_ 16

typedef __attribute__((ext_vector_type(8))) short short8;
typedef __attribute__((ext_vector_type(4))) float f32x4;
typedef __attribute__((ext_vector_type(4))) short s16x4;

__device__ __forceinline__ unsigned short f2bf(float f){
  union { float f; unsigned u; } c; c.f = f;
  unsigned u = c.u;
  return (unsigned short)((u + 0x7fffu + ((u >> 16) & 1u)) >> 16);
}

__device__ __forceinline__ unsigned pk_bf16(float lo, float hi){
  unsigned r;
  asm("v_cvt_pk_bf16_f32 %0, %1, %2" : "=v"(r) : "v"(lo), "v"(hi));
  return r;
}

__device__ __forceinline__ float fexp2(float x){
#if __has_builtin(__builtin_amdgcn_exp2f)
  return __builtin_amdgcn_exp2f(x);
#else
  return exp2f(x);
#endif
}

__device__ __forceinline__ f32x4 mfma16(short8 a, short8 b, f32x4 c){
  return __builtin_amdgcn_mfma_f32_16x16x32_bf16(a, b, c, 0, 0, 0);
}

// async global->LDS, 16B per lane; LDS dest must be uniform-base + lane*16
__device__ __forceinline__ void gload16(const void* g, void* l){
  __builtin_amdgcn_global_load_lds(
      (const __attribute__((address_space(1))) unsigned*)g,
      (__attribute__((address_space(3))) unsigned*)l, 16, 0, 0);
}

// ---------------- prep: f32 -> bf16 (8/thread, 16B stores) + rope table ------
__global__ __launch_bounds__(256) void k_prep(const float* __restrict__ x,
    const float* __restrict__ wq, const float* __restrict__ wk,
    const float* __restrict__ wv, const float* __restrict__ wo,
    unsigned short* __restrict__ xb, unsigned short* __restrict__ wqkv,
    unsigned short* __restrict__ wob, float* __restrict__ tab)
{
  if (blockIdx.x < 256){                      // rope table [T][32] sin|cos
    int i = blockIdx.x * 256 + threadIdx.x;
    int t = i >> 5, p = i & 31;
    float ang = (float)t * powf(10000.0f, -(float)p * (1.0f / 32.0f));
    tab[i] = sinf(ang);
    tab[T_ * 32 + i] = cosf(ang);
  }
  const long long NX = 4194304LL, NW = 1048576LL;
  long long base = ((long long)blockIdx.x * 256 + threadIdx.x) * 8;
  const float* s; unsigned short* d;
  if (base < NX){ s = x + base; d = xb + base; }
  else if (base < NX + 3*NW){
    long long j = base - NX;
    if (j < NW) s = wq + j;
    else if (j < 2*NW) s = wk + (j - NW);
    else s = wv + (j - 2*NW);
    d = wqkv + j;
  } else if (base < NX + 4*NW){
    long long j = base - NX - 3*NW;
    s = wo + j; d = wob + j;
  } else return;
  float4 a = *(const float4*)s;
  float4 b = *(const float4*)(s + 4);
  union { unsigned u[4]; short8 v; } o;
  o.u[0] = pk_bf16(a.x, a.y);
  o.u[1] = pk_bf16(a.z, a.w);
  o.u[2] = pk_bf16(b.x, b.y);
  o.u[3] = pk_bf16(b.z, b.w);
  *(short8*)d = o.v;
}

// ---------------- shared GEMM core (T3-min pipelined, R12-validated) ---------
__device__ __forceinline__ void gemm_core(const unsigned short* __restrict__ A,
    const unsigned short* __restrict__ Bm, int m0, int n0,
    unsigned short* lA0, unsigned short* lB0,
    unsigned short* lA1, unsigned short* lB1, f32x4 (&acc)[4][4])
{
  const int tid = threadIdx.x, lane = tid & 63, wave = tid >> 6;
  const int wr = wave >> 1, wc = wave & 1;
  for (int mi = 0; mi < 4; ++mi)
    for (int ni = 0; ni < 4; ++ni)
      acc[mi][ni] = (f32x4){0.f, 0.f, 0.f, 0.f};

  auto STAGE = [&](int k0, unsigned short* lA, unsigned short* lB){
#pragma unroll
    for (int p = 0; p < 4; ++p){
      int c = p * 256 + tid, r = c >> 3, s = c & 7;
      int gs = (s ^ (r & 7)) << 3;
      gload16(A + (size_t)(m0 + r) * 1024 + k0 + gs, lA + c * 8);
      gload16(Bm + (size_t)(n0 + r) * 1024 + k0 + gs, lB + c * 8);
    }
  };
  auto COMPUTE = [&](const unsigned short* lA, const unsigned short* lB){
#pragma unroll
    for (int kk = 0; kk < 2; ++kk){
      int kslot = kk * 4 + (lane >> 4);
      short8 af[4], bf[4];
#pragma unroll
      for (int mi = 0; mi < 4; ++mi){
        int row = wr * 64 + mi * 16 + (lane & 15);
        af[mi] = *(const short8*)(lA + row * 64 + ((kslot ^ (row & 7)) << 3));
      }
#pragma unroll
      for (int ni = 0; ni < 4; ++ni){
        int row = wc * 64 + ni * 16 + (lane & 15);
        bf[ni] = *(const short8*)(lB + row * 64 + ((kslot ^ (row & 7)) << 3));
      }
#pragma unroll
      for (int mi = 0; mi < 4; ++mi)
#pragma unroll
        for (int ni = 0; ni < 4; ++ni)
          acc[mi][ni] = mfma16(af[mi], bf[ni], acc[mi][ni]);
    }
  };

  STAGE(0, lA0, lB0);
  asm volatile("s_waitcnt vmcnt(0)" ::: "memory");
  __builtin_amdgcn_s_barrier();
  for (int k0 = 0; k0 < 1024; k0 += 64){
    bool ev = !((k0 >> 6) & 1);
    if (k0 + 64 < 1024)                     // prefetch flies under compute
      STAGE(k0 + 64, ev ? lA1 : lA0, ev ? lB1 : lB0);
    COMPUTE(ev ? lA0 : lA1, ev ? lB0 : lB1);
    asm volatile("s_waitcnt vmcnt(0)" ::: "memory");  // own prefetch done
    __builtin_amdgcn_s_barrier();           // reads(k) done ∧ k+1 visible
  }
}

// ---------------- fused QKV projection + bias + RoPE (R2 epilogue) -----------
__global__ __launch_bounds__(256) void k_qkv(const unsigned short* __restrict__ xb,
    const unsigned short* __restrict__ wqkv,
    const float* __restrict__ bq, const float* __restrict__ bk, const float* __restrict__ bv,
    const float* __restrict__ tab,
    unsigned short* __restrict__ Qw, unsigned short* __restrict__ Kw,
    unsigned short* __restrict__ Vw)
{
  __shared__ alignas(16) unsigned short lA0[128 * 64];
  __shared__ alignas(16) unsigned short lB0[128 * 64];
  __shared__ alignas(16) unsigned short lA1[128 * 64];
  __shared__ alignas(16) unsigned short lB1[128 * 64];
  int m0 = blockIdx.y * 128, n0 = blockIdx.x * 128;
  f32x4 acc[4][4];
  gemm_core(xb, wqkv, m0, n0, lA0, lB0, lA1, lB1, acc);
  int lane = threadIdx.x & 63, wave = threadIdx.x >> 6;
  int wr = wave >> 1, wc = wave & 1;
  int mat = n0 >> 10;                       // 0=Q 1=K 2=V
  const float* bias = (mat == 0) ? bq : (mat == 1 ? bk : bv);
  const float* st = tab; const float* ct = tab + T_ * 32;
  if (mat < 2){
    unsigned short* Out = (mat == 0) ? Qw : Kw;
    float qs = (mat == 0) ? 0.18033688011116f : 1.0f;   // (1/8)*log2e
    for (int mi = 0; mi < 4; ++mi){
      for (int ni = 0; ni < 4; ++ni){
        int col = n0 + wc * 64 + ni * 16 + (lane & 15);
        int nn = col & 1023, h = nn >> 6, dd = nn & 63;
        float bsv = bias[nn];
        f32x4 v4 = acc[mi][ni];
#pragma unroll
        for (int r = 0; r < 4; ++r){
          int m = m0 + wr * 64 + mi * 16 + ((lane >> 4) << 2) + r;
          int bb = m >> 11, t = m & 2047;
          float v = v4[r] + bsv;
          float u = __shfl_xor(v, 1);       // rope partner col is lane^1
          int p = dd >> 1;
          float sv = st[t * 32 + p], cv = ct[t * 32 + p];
          float res = (dd & 1) ? (u * sv + v * cv) : (v * cv - u * sv);
          Out[((size_t)(bb * H_ + h) * T_ + t) * 64 + dd] = f2bf(res * qs);
        }
      }
    }
  } else {
    for (int mi = 0; mi < 4; ++mi){
      for (int ni = 0; ni < 4; ++ni){
        int col = n0 + wc * 64 + ni * 16 + (lane & 15);
        int nn = col & 1023, h = nn >> 6, dd = nn & 63;
        float bsv = bias[nn];
        int mb = m0 + wr * 64 + mi * 16 + ((lane >> 4) << 2);
        int bb = mb >> 11, t = mb & 2047;
        f32x4 v4 = acc[mi][ni];
        s16x4 o;
#pragma unroll
        for (int r = 0; r < 4; ++r) o[r] = (short)f2bf(v4[r] + bsv);
        *(s16x4*)(Vw + ((size_t)((bb * H_ + h) * 64 + dd)) * T_ + t) = o;
      }
    }
  }
}

// ---------------- flash attention: fused pair, 256-row staged KV, setprio ----
__global__ __launch_bounds__(512) void k_attn(const unsigned short* __restrict__ Qw,
    const unsigned short* __restrict__ Kw, const unsigned short* __restrict__ Vt_g,
    unsigned short* __restrict__ ctxb)
{
  __shared__ alignas(16) unsigned short Kl0[256 * 64];   // [j][d] swizzled, 32KB
  __shared__ alignas(16) unsigned short Vl0[64 * 256];   // [d][j] swizzled, 32KB
  __shared__ alignas(16) unsigned short Kl1[256 * 64];
  __shared__ alignas(16) unsigned short Vl1[64 * 256];
  int bh = blockIdx.x;
  int yy = blockIdx.y;                      // 0..7, heavy pairs first
  int qtH = 15 - yy, qtL = yy;
  int tid = threadIdx.x, lane = tid & 63, wave = tid >> 6;   // 8 waves
  const unsigned short* Qb = Qw + (size_t)bh * T_ * 64;
  const unsigned short* Kb = Kw + (size_t)bh * T_ * 64;
  const unsigned short* Vb = Vt_g + (size_t)bh * 64 * T_;
  const int qb[2] = { qtH * 128 + wave * 16, qtL * 128 + wave * 16 };

  short8 qf[2][2];
#pragma unroll
  for (int mi = 0; mi < 2; ++mi){
    const unsigned short* qp = Qb + (size_t)(qb[mi] + (lane & 15)) * 64 + ((lane >> 4) << 3);
    qf[mi][0] = *(const short8*)qp;
    qf[mi][1] = *(const short8*)(qp + 32);
  }
  float mr[2] = {-1e30f, -1e30f}, lr[2] = {0.f, 0.f};
  f32x4 acc_o[2][4];
#pragma unroll
  for (int mi = 0; mi < 2; ++mi)
#pragma unroll
    for (int df = 0; df < 4; ++df) acc_o[mi][df] = (f32x4){0.f, 0.f, 0.f, 0.f};

  const int src0 = ((lane >> 4) & 1) * 32 + (lane & 15);
  const int src1 = src0 + 16;
  const bool hiHalf = lane >= 32;

  auto STAGE = [&](int j0, unsigned short* Kd, unsigned short* Vd){
#pragma unroll
    for (int p = 0; p < 4; ++p){
      int c = p * 512 + tid;                // 0..2047
      int rK = c >> 3, sK = c & 7;          // K: 256 rows x 8 slots
      gload16(Kb + (size_t)(j0 + rK) * 64 + ((sK ^ (rK & 7)) << 3), Kd + c * 8);
      int rV = c >> 5, sV = c & 31;         // V^T: 64 rows x 32 slots
      gload16(Vb + (size_t)rV * T_ + j0 + ((sV ^ (rV & 7)) << 3), Vd + c * 8);
    }
  };

  auto COMPUTE = [&](int j0, const unsigned short* Kc, const unsigned short* Vc){
    bool act[2] = { j0 <= qb[0] + 15, j0 <= qb[1] + 15 };
    if (!act[0] && !act[1]) return;
    f32x4 accs[2][8];
#pragma unroll
    for (int mi = 0; mi < 2; ++mi)
#pragma unroll
      for (int jf = 0; jf < 8; ++jf) accs[mi][jf] = (f32x4){0.f, 0.f, 0.f, 0.f};
#pragma unroll
    for (int kk = 0; kk < 2; ++kk){
      int kslot = kk * 4 + (lane >> 4);
      short8 kf[8];
#pragma unroll
      for (int jf = 0; jf < 8; ++jf){
        int row = jf * 16 + (lane & 15);
        kf[jf] = *(const short8*)(Kc + row * 64 + ((kslot ^ (row & 7)) << 3));
      }
      __builtin_amdgcn_s_setprio(1);
#pragma unroll
      for (int mi = 0; mi < 2; ++mi)
        if (act[mi])
#pragma unroll
          for (int jf = 0; jf < 8; ++jf)
            accs[mi][jf] = mfma16(kf[jf], qf[mi][kk], accs[mi][jf]);
      __builtin_amdgcn_s_setprio(0);
    }

    unsigned w0[2][8], w1[2][8];
#pragma unroll
    for (int mi = 0; mi < 2; ++mi){
      if (!act[mi]) continue;
      int qa = qb[mi] + (lane & 15);
      bool need_mask = (j0 + 127 > qb[mi]);
      // masked max, tree-reduced (depth 5 instead of serial 32)
      float m8[8];
#pragma unroll
      for (int jf = 0; jf < 8; ++jf){
        f32x4 a = accs[mi][jf];
        if (need_mask){
          int jbase = j0 + jf * 16 + ((lane >> 4) << 2);
#pragma unroll
          for (int r = 0; r < 4; ++r)
            if (jbase + r > qa) a[r] = -1e30f;
          accs[mi][jf] = a;
        }
        m8[jf] = fmaxf(fmaxf(a[0], a[1]), fmaxf(a[2], a[3]));
      }
      float mx = fmaxf(fmaxf(fmaxf(m8[0], m8[1]), fmaxf(m8[2], m8[3])),
                       fmaxf(fmaxf(m8[4], m8[5]), fmaxf(m8[6], m8[7])));
      mx = fmaxf(mx, __shfl_xor(mx, 16));
      mx = fmaxf(mx, __shfl_xor(mx, 32));
      float mn = mr[mi];
      if (!__all(mx <= mn + 8.0f)){         // defer-max: rescale only on growth
        mn = fmaxf(mn, mx);
        float sc = fexp2(mr[mi] - mn);
        mr[mi] = mn;
        lr[mi] *= sc;
#pragma unroll
        for (int df = 0; df < 4; ++df){
          f32x4 a = acc_o[mi][df];
          a[0] *= sc; a[1] *= sc; a[2] *= sc; a[3] *= sc;
          acc_o[mi][df] = a;
        }
      }
      // exp + tree sum (depth 5 instead of serial 32)
      float s8[8];
#pragma unroll
      for (int jf = 0; jf < 8; ++jf){
        f32x4 a = accs[mi][jf];
        a[0] = fexp2(a[0] - mn); a[1] = fexp2(a[1] - mn);
        a[2] = fexp2(a[2] - mn); a[3] = fexp2(a[3] - mn);
        accs[mi][jf] = a;
        s8[jf] = (a[0] + a[1]) + (a[2] + a[3]);
      }
      float rs = ((s8[0] + s8[1]) + (s8[2] + s8[3])) +
                 ((s8[4] + s8[5]) + (s8[6] + s8[7]));
      rs += __shfl_xor(rs, 16);
      rs += __shfl_xor(rs, 32);
      lr[mi] += rs;
#pragma unroll
      for (int jf = 0; jf < 8; ++jf){
        w0[mi][jf] = pk_bf16(accs[mi][jf][0], accs[mi][jf][1]);
        w1[mi][jf] = pk_bf16(accs[mi][jf][2], accs[mi][jf][3]);
      }
    }

#pragma unroll
    for (int kk = 0; kk < 4; ++kk){
      int jslot = kk * 4 + (lane >> 4);
      short8 vf[4];
#pragma unroll
      for (int df = 0; df < 4; ++df){
        int row = df * 16 + (lane & 15);
        vf[df] = *(const short8*)(Vc + row * 256 + ((jslot ^ (row & 7)) << 3));
      }
#pragma unroll
      for (int mi = 0; mi < 2; ++mi){
        if (!act[mi]) continue;
        unsigned lo0 = (unsigned)__shfl((int)w0[mi][2*kk],   src0);
        unsigned hi0 = (unsigned)__shfl((int)w0[mi][2*kk+1], src0);
        unsigned lo1 = (unsigned)__shfl((int)w1[mi][2*kk],   src0);
        unsigned hi1 = (unsigned)__shfl((int)w1[mi][2*kk+1], src0);
        unsigned lo2 = (unsigned)__shfl((int)w0[mi][2*kk],   src1);
        unsigned hi2 = (unsigned)__shfl((int)w0[mi][2*kk+1], src1);
        unsigned lo3 = (unsigned)__shfl((int)w1[mi][2*kk],   src1);
        unsigned hi3 = (unsigned)__shfl((int)w1[mi][2*kk+1], src1);
        union { unsigned u[4]; short8 v; } pb;
        pb.u[0] = hiHalf ? hi0 : lo0;
        pb.u[1] = hiHalf ? hi1 : lo1;
        pb.u[2] = hiHalf ? hi2 : lo2;
        pb.u[3] = hiHalf ? hi3 : lo3;
        __builtin_amdgcn_s_setprio(1);
#pragma unroll
        for (int df = 0; df < 4; ++df)
          acc_o[mi][df] = mfma16(vf[df], pb.v, acc_o[mi][df]);
        __builtin_amdgcn_s_setprio(0);
      }
    }
  };

  int ntiles = (qtH + 2) >> 1;              // 256-row tiles covering heavy range
  STAGE(0, Kl0, Vl0);
  asm volatile("s_waitcnt vmcnt(0)" ::: "memory");
  __builtin_amdgcn_s_barrier();
  for (int jt = 0; jt < ntiles; ++jt){
    bool ev = !(jt & 1);
    unsigned short* Kc = ev ? Kl0 : Kl1;
    unsigned short* Vc = ev ? Vl0 : Vl1;
    if (jt + 1 < ntiles)                    // prefetch flies under both halves
      STAGE((jt + 1) * 256, ev ? Kl1 : Kl0, ev ? Vl1 : Vl0);
    COMPUTE(jt * 256,       Kc,            Vc);        // half 0
    COMPUTE(jt * 256 + 128, Kc + 128 * 64, Vc + 128);  // half 1
    asm volatile("s_waitcnt vmcnt(0)" ::: "memory");   // own prefetch done
    __builtin_amdgcn_s_barrier();           // reads(jt) done ∧ jt+1 visible
  }

  int bb = bh >> 4, h = bh & 15;
#pragma unroll
  for (int mi = 0; mi < 2; ++mi){
    float inv = 1.0f / lr[mi];
    int t = qb[mi] + (lane & 15);
#pragma unroll
    for (int df = 0; df < 4; ++df){
      int d0 = df * 16 + ((lane >> 4) << 2);
      f32x4 a = acc_o[mi][df];
      s16x4 o;
#pragma unroll
      for (int r = 0; r < 4; ++r) o[r] = (short)f2bf(a[r] * inv);
      *(s16x4*)(ctxb + ((size_t)(bb * T_ + t)) * 1024 + h * 64 + d0) = o;
    }
  }
}

// ---------------- output projection (R2 epilogue) ----------------
__global__ __launch_bounds__(256) void k_oproj(const unsigned short* __restrict__ ctxb,
    const unsigned short* __restrict__ wob, const float* __restrict__ bo,
    float* __restrict__ out)
{
  __shared__ alignas(16) unsigned short lA0[128 * 64];
  __shared__ alignas(16) unsigned short lB0[128 * 64];
  __shared__ alignas(16) unsigned short lA1[128 * 64];
  __shared__ alignas(16) unsigned short lB1[128 * 64];
  int m0 = blockIdx.y * 128, n0 = blockIdx.x * 128;
  f32x4 acc[4][4];
  gemm_core(ctxb, wob, m0, n0, lA0, lB0, lA1, lB1, acc);
  int lane = threadIdx.x & 63, wave = threadIdx.x >> 6;
  int wr = wave >> 1, wc = wave & 1;
  for (int mi = 0; mi < 4; ++mi)
    for (int ni = 0; ni < 4; ++ni){
      int col = n0 + wc * 64 + ni * 16 + (lane & 15);
      float bsv = bo[col];
      f32x4 v4 = acc[mi][ni];
#pragma unroll
      for (int r = 0; r < 4; ++r){
        int m = m0 + wr * 64 + mi * 16 + ((lane >> 4) << 2) + r;
        out[(size_t)m * 1024 + col] = v4[r] + bsv;
      }
    }
}

extern "C" void kernel_launch(void* const* d_in, const int* in_sizes, int n_in,
                              void* d_out, int out_size, void* d_ws, size_t ws_size,
                              hipStream_t stream)
{
  const float* x  = (const float*)d_in[0];
  const float* wq = (const float*)d_in[1];
  const float* bq = (const float*)d_in[2];
  const float* wk = (const float*)d_in[3];
  const float* bk = (const float*)d_in[4];
  const float* wv = (const float*)d_in[5];
  const float* bv = (const float*)d_in[6];
  const float* wo = (const float*)d_in[7];
  const float* bo = (const float*)d_in[8];
  char* w = (char*)d_ws;
  unsigned short* xb   = (unsigned short*)(w);               // 8 MiB  [4096][1024]
  unsigned short* wqkv = (unsigned short*)(w + (8 << 20));   // 6 MiB  [3072][1024]
  unsigned short* wob  = (unsigned short*)(w + (14 << 20));  // 2 MiB
  unsigned short* Qw   = (unsigned short*)(w + (16 << 20));  // 8 MiB  [B,H,T,DK]
  unsigned short* Kw   = (unsigned short*)(w + (24 << 20));  // 8 MiB  [B,H,T,DK]
  unsigned short* Vw   = (unsigned short*)(w + (32 << 20));  // 8 MiB  [B,H,DK,T] (transposed!)
  unsigned short* ctxb = (unsigned short*)(w + (40 << 20));  // 8 MiB  [B,T,D]
  float* tab           = (float*)(w + (48 << 20));           // 512 KiB sin|cos

  k_prep<<<4096, 256, 0, stream>>>(x, wq, wk, wv, wo, xb, wqkv, wob, tab);
  k_qkv<<<dim3(24, 32), 256, 0, stream>>>(xb, wqkv, bq, bk, bv, tab, Qw, Kw, Vw);
  k_attn<<<dim3(32, 8), 512, 0, stream>>>(Qw, Kw, Vw, ctxb);
  k_oproj<<<dim3(8, 32), 256, 0, stream>>>(ctxb, wob, bo, (float*)d_out);
}